// Round 8
// baseline (699.188 us; speedup 1.0000x reference)
//
#include <hip/hip_runtime.h>
#include <hip/hip_bf16.h>
#include <stdint.h>

typedef __hip_bfloat16 bf16;
typedef __attribute__((ext_vector_type(8))) short short8;
typedef __attribute__((ext_vector_type(4))) float f32x4;

#define NB 32768
#define NC 1024
#define NH 1024
#define NS 8
#define NDC 64

__device__ __forceinline__ void gload_lds16(const void* g, void* l) {
    __builtin_amdgcn_global_load_lds((const __attribute__((address_space(1))) void*)g,
                                     (__attribute__((address_space(3))) void*)l, 16, 0, 0);
}

__device__ __forceinline__ short f2bf(float x) {
    bf16 h = __float2bfloat16(x);
    short s;
    __builtin_memcpy(&s, &h, 2);
    return s;
}

// ---------------- merged preprocessing: 3 transposes + style_contrib ----------------
// blocks [0,1024):    W1T[n][k]    = Wa1[k][n]         (32x32 tiles)
// blocks [1024,2048): W2T[n][k]    = Wa2[k][n]
// blocks [2048,2560): Wc1T[s*64+d][c] = Wc1[s][c][d]   (batched, 8 styles)
// blocks [2560,2564): style_contrib[s][h] = ba1[h] + sum_k style_emb[s][k]*Wa1[C+k][h]
__global__ __launch_bounds__(256) void prep_kernel(
    const float* __restrict__ Wa1, const float* __restrict__ Wa2,
    const float* __restrict__ Wc1, const float* __restrict__ style_emb,
    const float* __restrict__ ba1,
    bf16* __restrict__ W1T, bf16* __restrict__ W2T, bf16* __restrict__ Wc1T,
    float* __restrict__ style_contrib)
{
    __shared__ float tile[32][33];
    const int b = blockIdx.x;
    const int tx = threadIdx.x, ty = threadIdx.y;  // 32 x 8

    if (b < 2560) {
        const float* in; bf16* out; int R, Ccols, bx, by;
        long long ioff = 0, ooff = 0;
        if (b < 1024) {
            in = Wa1; out = W1T; R = NC; Ccols = NH; bx = b & 31; by = b >> 5;
        } else if (b < 2048) {
            const int i = b - 1024;
            in = Wa2; out = W2T; R = NH; Ccols = NC; bx = i & 31; by = i >> 5;
        } else {
            const int i = b - 2048;
            const int bz = i >> 6, rem = i & 63;
            by = rem >> 1; bx = rem & 1;
            in = Wc1; out = Wc1T; R = NC; Ccols = NDC;
            ioff = (long long)bz * NC * NDC; ooff = (long long)bz * NDC * NC;
        }
        const float* inb = in + ioff;
        bf16* outb = out + ooff;
        const int c0 = bx * 32, r0 = by * 32;
#pragma unroll
        for (int i = 0; i < 32; i += 8)
            tile[ty + i][tx] = inb[(size_t)(r0 + ty + i) * Ccols + c0 + tx];
        __syncthreads();
#pragma unroll
        for (int i = 0; i < 32; i += 8)
            outb[(size_t)(c0 + ty + i) * R + r0 + tx] = __float2bfloat16(tile[tx][ty + i]);
    } else {
        const int t = ty * 32 + tx;
        const int h = (b - 2560) * 256 + t;
        float acc[NS];
#pragma unroll
        for (int s = 0; s < NS; ++s) acc[s] = 0.f;
#pragma unroll 4
        for (int k = 0; k < NH; ++k) {
            const float w = Wa1[(size_t)(NC + k) * NH + h];
#pragma unroll
            for (int s = 0; s < NS; ++s)
                acc[s] += style_emb[s * NH + k] * w;
        }
#pragma unroll
        for (int s = 0; s < NS; ++s)
            style_contrib[s * NH + h] = ba1[h] + acc[s];
    }
}

// ---------------- BK=64 bf16 GEMM (2-barrier proven structure) ----------------
// MODE 0: A f32 (logits), reg-staged f32->bf16 (T14 issue-early);
//         out bf16 = relu(acc + style_contrib[idx[row]][col])
// MODE 1: A bf16 via gload_lds; f32 out = acc + resid[row][col] + bias[col]
// MODE 2: A f32 (adjusted); FUSED SOFTMAX during reg-staging (row stats
//         pre-pass in LDS, exp(x-m)*inv_s at conversion); conf fused epilogue.
//
// LDS swizzle (G4, 128B rows): phys_chunk = logical_chunk ^ (row&7); applied
// as permuted global source (gload path), swizzled ds_write (reg path), and
// swizzled ds_read. T14 ledger (MODE 0/2): issue A-loads(t+1) -> MFMA(t) ->
// barrier (WAR + drains loads, hidden under MFMA) -> ds_write A(t+1) +
// gload B(t+1) -> barrier (RAW drain). Two barriers/iter, same as proven R6.
template<int MODE>
__global__ __launch_bounds__(256, 2) void gemm_kernel(
    const void* __restrict__ Ain, const bf16* __restrict__ BT,
    bf16* __restrict__ Cb, float* __restrict__ Cf,
    int N, int K,
    const float* __restrict__ style_contrib, const int* __restrict__ style_idx,
    const float* __restrict__ resid, const float* __restrict__ bias,
    const float* __restrict__ bc1, const float* __restrict__ Wc2,
    const float* __restrict__ bc2, float* __restrict__ conf_out)
{
    __shared__ short lA[128 * 64];   // 16 KB
    __shared__ short lB[128 * 64];   // 16 KB
    __shared__ float sm_m[128];
    __shared__ float sm_is[128];

    const int t = threadIdx.x;
    const int lane = t & 63;
    const int wave = t >> 6;
    const int wr = wave >> 1;
    const int wc = wave & 1;

    // T1: XCD-aware swizzle (nwg divisible by 8)
    const int nwg = gridDim.x * gridDim.y;
    const int flat = blockIdx.y * gridDim.x + blockIdx.x;
    const int cpx = nwg >> 3;
    const int swz = (flat & 7) * cpx + (flat >> 3);
    const int bm0 = (swz / gridDim.x) * 128;
    const int bn0 = (swz % gridDim.x) * 128;

    const int r08 = t >> 3;
    const int clog = t & 7;
    const int csrc = clog ^ (r08 & 7);

    const int mrow = lane & 15;
    const int quad = lane >> 4;
    const int mrow7 = mrow & 7;

    f32x4 acc[4][4];
#pragma unroll
    for (int i = 0; i < 4; ++i)
#pragma unroll
        for (int j = 0; j < 4; ++j) acc[i][j] = (f32x4){0.f, 0.f, 0.f, 0.f};

    const float* gAf = (const float*)Ain + (size_t)(bm0 + r08) * K + clog * 8;
    const bf16*  gAb = (const bf16*)Ain + (size_t)(bm0 + r08) * K + csrc * 8;
    const bf16*  gB  = BT + (size_t)(bn0 + r08) * K + csrc * 8;

    // ---- MODE 2: softmax row-stats pre-pass (wave w -> rows w*32..w*32+31) ----
    if (MODE == 2) {
        for (int rr = 0; rr < 32; ++rr) {
            const int row = wave * 32 + rr;
            const float* x = (const float*)Ain + (size_t)(bm0 + row) * K + lane * 4;
            float4 v0 = *(const float4*)(x);
            float4 v1 = *(const float4*)(x + 256);
            float4 v2 = *(const float4*)(x + 512);
            float4 v3 = *(const float4*)(x + 768);
            float m = fmaxf(fmaxf(fmaxf(v0.x, v0.y), fmaxf(v0.z, v0.w)),
                            fmaxf(fmaxf(v1.x, v1.y), fmaxf(v1.z, v1.w)));
            m = fmaxf(m, fmaxf(fmaxf(fmaxf(v2.x, v2.y), fmaxf(v2.z, v2.w)),
                               fmaxf(fmaxf(v3.x, v3.y), fmaxf(v3.z, v3.w))));
#pragma unroll
            for (int off = 1; off < 64; off <<= 1) m = fmaxf(m, __shfl_xor(m, off, 64));
            float s = __expf(v0.x - m) + __expf(v0.y - m) + __expf(v0.z - m) + __expf(v0.w - m)
                    + __expf(v1.x - m) + __expf(v1.y - m) + __expf(v1.z - m) + __expf(v1.w - m)
                    + __expf(v2.x - m) + __expf(v2.y - m) + __expf(v2.z - m) + __expf(v2.w - m)
                    + __expf(v3.x - m) + __expf(v3.y - m) + __expf(v3.z - m) + __expf(v3.w - m);
#pragma unroll
            for (int off = 1; off < 64; off <<= 1) s += __shfl_xor(s, off, 64);
            if (lane == 0) { sm_m[row] = m; sm_is[row] = 1.0f / s; }
        }
        __syncthreads();
    }

    const int NT = K >> 6;
    float4 arA[4], arB[4];

#define LOADA(kt)                                                              \
    do {                                                                       \
        _Pragma("unroll")                                                      \
        for (int q = 0; q < 4; ++q) {                                          \
            const float* src_ = gAf + (size_t)q * 32 * K + (kt) * 64;          \
            arA[q] = *(const float4*)(src_);                                   \
            arB[q] = *(const float4*)(src_ + 4);                               \
        }                                                                      \
    } while (0)

#define WRITEA()                                                               \
    do {                                                                       \
        _Pragma("unroll")                                                      \
        for (int q = 0; q < 4; ++q) {                                          \
            const int row_ = q * 32 + r08;                                     \
            float e0 = arA[q].x, e1 = arA[q].y, e2 = arA[q].z, e3 = arA[q].w;  \
            float e4 = arB[q].x, e5 = arB[q].y, e6 = arB[q].z, e7 = arB[q].w;  \
            if (MODE == 2) {                                                   \
                const float m_ = sm_m[row_], is_ = sm_is[row_];                \
                e0 = __expf(e0 - m_) * is_; e1 = __expf(e1 - m_) * is_;        \
                e2 = __expf(e2 - m_) * is_; e3 = __expf(e3 - m_) * is_;        \
                e4 = __expf(e4 - m_) * is_; e5 = __expf(e5 - m_) * is_;        \
                e6 = __expf(e6 - m_) * is_; e7 = __expf(e7 - m_) * is_;        \
            }                                                                  \
            short8 v_;                                                         \
            v_[0] = f2bf(e0); v_[1] = f2bf(e1); v_[2] = f2bf(e2); v_[3] = f2bf(e3); \
            v_[4] = f2bf(e4); v_[5] = f2bf(e5); v_[6] = f2bf(e6); v_[7] = f2bf(e7); \
            *(short8*)(lA + row_ * 64 + (clog ^ (r08 & 7)) * 8) = v_;          \
        }                                                                      \
    } while (0)

#define STAGEB(kt)                                                             \
    do {                                                                       \
        _Pragma("unroll")                                                      \
        for (int q = 0; q < 4; ++q)                                            \
            gload_lds16(gB + (size_t)q * 32 * K + (kt) * 64, lB + q * 2048 + t * 8); \
    } while (0)

#define COMPUTE()                                                              \
    do {                                                                       \
        _Pragma("unroll")                                                      \
        for (int kk = 0; kk < 2; ++kk) {                                       \
            const int coff = ((kk * 4 + quad) ^ mrow7) * 8;                    \
            short8 af[4], bfr[4];                                              \
            _Pragma("unroll")                                                  \
            for (int i = 0; i < 4; ++i)                                        \
                af[i] = *(const short8*)(lA + (wr * 64 + i * 16 + mrow) * 64 + coff); \
            _Pragma("unroll")                                                  \
            for (int j = 0; j < 4; ++j)                                        \
                bfr[j] = *(const short8*)(lB + (wc * 64 + j * 16 + mrow) * 64 + coff); \
            _Pragma("unroll")                                                  \
            for (int i = 0; i < 4; ++i)                                        \
                _Pragma("unroll")                                              \
                for (int j = 0; j < 4; ++j)                                    \
                    acc[i][j] = __builtin_amdgcn_mfma_f32_16x16x32_bf16(af[i], bfr[j], acc[i][j], 0, 0, 0); \
        }                                                                      \
    } while (0)

    if (MODE == 1) {
        for (int kt = 0; kt < NT; ++kt) {
#pragma unroll
            for (int q = 0; q < 4; ++q)
                gload_lds16(gAb + (size_t)q * 32 * K + kt * 64, lA + q * 2048 + t * 8);
            STAGEB(kt);
            __syncthreads();
            COMPUTE();
            __syncthreads();
        }
    } else {
        // T14: prologue stages tile 0; loop issues A-loads(t+1) before MFMA(t)
        LOADA(0);
        WRITEA();
        STAGEB(0);
        __syncthreads();
        for (int kt = 0; kt < NT; ++kt) {
            if (kt + 1 < NT) LOADA(kt + 1);   // in flight across COMPUTE
            COMPUTE();
            if (kt + 1 < NT) {
                __syncthreads();              // WAR on lA/lB; drains A-loads
                WRITEA();
                STAGEB(kt + 1);
                __syncthreads();              // RAW: B landed, A writes visible
            }
        }
    }
#undef LOADA
#undef WRITEA
#undef STAGEB
#undef COMPUTE

    if (MODE == 2) {
        // this wave-half covers style s_w completely (cols s_w*64 .. s_w*64+63)
        const int s_w = (bn0 >> 6) + wc;
        float bcv[4], wcv[4];
#pragma unroll
        for (int j = 0; j < 4; ++j) {
            const int d = j * 16 + mrow;
            bcv[j] = bc1[s_w * NDC + d];
            wcv[j] = Wc2[s_w * NDC + d];
        }
        const float bias2 = bc2[s_w];
#pragma unroll
        for (int i = 0; i < 4; ++i) {
#pragma unroll
            for (int r = 0; r < 4; ++r) {
                const int grow = bm0 + wr * 64 + i * 16 + quad * 4 + r;
                float p = 0.f;
#pragma unroll
                for (int j = 0; j < 4; ++j)
                    p += fmaxf(acc[i][j][r] + bcv[j], 0.f) * wcv[j];
#pragma unroll
                for (int off = 1; off < 16; off <<= 1) p += __shfl_xor(p, off, 64);
                if (mrow == 0 && style_idx[grow] == s_w)
                    conf_out[grow] = 1.0f / (1.0f + __expf(-(p + bias2)));
            }
        }
        return;
    }

    // epilogue: C/D layout col = lane&15, row = quad*4 + reg
#pragma unroll
    for (int i = 0; i < 4; ++i) {
#pragma unroll
        for (int r = 0; r < 4; ++r) {
            const int grow = bm0 + wr * 64 + i * 16 + quad * 4 + r;
            const float* scrow = nullptr;
            const float* resrow = nullptr;
            if (MODE == 0) scrow = style_contrib + (size_t)style_idx[grow] * N;
            if (MODE == 1) resrow = resid + (size_t)grow * N;
#pragma unroll
            for (int j = 0; j < 4; ++j) {
                const int gcol = bn0 + wc * 64 + j * 16 + mrow;
                float v = acc[i][j][r];
                if (MODE == 0) {
                    v += scrow[gcol];
                    v = fmaxf(v, 0.f);
                    Cb[(size_t)grow * N + gcol] = __float2bfloat16(v);
                } else {
                    v += resrow[gcol] + bias[gcol];
                    Cf[(size_t)grow * N + gcol] = v;
                }
            }
        }
    }
}

extern "C" void kernel_launch(void* const* d_in, const int* in_sizes, int n_in,
                              void* d_out, int out_size, void* d_ws, size_t ws_size,
                              hipStream_t stream) {
    const float* logits    = (const float*)d_in[0];
    const int*   style_idx = (const int*)d_in[1];
    const float* style_emb = (const float*)d_in[2];
    const float* Wa1       = (const float*)d_in[3];
    const float* ba1       = (const float*)d_in[4];
    const float* Wa2       = (const float*)d_in[5];
    const float* ba2       = (const float*)d_in[6];
    const float* Wc1       = (const float*)d_in[7];
    const float* bc1       = (const float*)d_in[8];
    const float* Wc2       = (const float*)d_in[9];
    const float* bc2       = (const float*)d_in[10];

    char* ws = (char*)d_ws;
    bf16* hidden = (bf16*)ws;          ws += (size_t)NB * NH * 2;          // 64 MB
    bf16* W1T = (bf16*)ws;             ws += (size_t)NC * NH * 2;          // 2 MB
    bf16* W2T = (bf16*)ws;             ws += (size_t)NH * NC * 2;          // 2 MB
    bf16* Wc1T = (bf16*)ws;            ws += (size_t)NS * NDC * NC * 2;    // 1 MB
    float* style_contrib = (float*)ws; ws += (size_t)NS * NH * 4;          // 32 KB

    float* adjusted = (float*)d_out;
    float* conf_out = (float*)d_out + (size_t)NB * NC;

    // all preprocessing in one dispatch: W1T, W2T, Wc1T transposes + style_contrib
    prep_kernel<<<2564, dim3(32, 8), 0, stream>>>(
        Wa1, Wa2, Wc1, style_emb, ba1, W1T, W2T, Wc1T, style_contrib);

    // hidden = relu(logits @ Wa1[:C] + style_contrib[style]); f32 A converted in-kernel
    gemm_kernel<0><<<dim3(NH / 128, NB / 128), 256, 0, stream>>>(
        logits, W1T, hidden, nullptr, NH, NC, style_contrib, style_idx, nullptr, nullptr,
        nullptr, nullptr, nullptr, nullptr);
    // adjusted = logits + hidden @ Wa2 + ba2
    gemm_kernel<1><<<dim3(NC / 128, NB / 128), 256, 0, stream>>>(
        hidden, W2T, nullptr, adjusted, NC, NH, nullptr, nullptr, logits, ba2,
        nullptr, nullptr, nullptr, nullptr);
    // conf = sigmoid(relu(softmax(adjusted) @ Wc1 + bc1) . Wc2 + bc2)
    // softmax fused into A-staging (stats pre-pass + exp at conversion)
    gemm_kernel<2><<<dim3((NS * NDC) / 128, NB / 128), 256, 0, stream>>>(
        adjusted, Wc1T, nullptr, nullptr, NS * NDC, NC, nullptr, style_idx, nullptr, nullptr,
        bc1, Wc2, bc2, conf_out);
}